// Round 1
// 11222.820 us; speedup vs baseline: 1.3720x; 1.3720x over previous
//
#include <hip/hip_runtime.h>

// Problem constants
#define BB 4
#define TT 2048
#define HH 512
#define GH 2048       // 4*H
#define VV 32000
#define MM 8192       // B*T
#define LBLK 64       // LSTM persistent blocks

typedef unsigned short u16;
typedef short bfrag8 __attribute__((ext_vector_type(8)));   // 8 x bf16 MFMA operand
typedef float f32x4  __attribute__((ext_vector_type(4)));   // MFMA accumulator

static __device__ __forceinline__ u16 f2bf(float f) {
    unsigned x = __float_as_uint(f);
    unsigned r = x + 0x7fffu + ((x >> 16) & 1u);   // round-to-nearest-even
    return (u16)(r >> 16);
}
static __device__ __forceinline__ float bf2f(u16 u) {
    return __uint_as_float(((unsigned)u) << 16);
}
static __device__ __forceinline__ float sigm(float x) {
    return 1.0f / (1.0f + __expf(-x));
}
static __device__ __forceinline__ float tanh_f(float x) {
    x = fminf(fmaxf(x, -30.f), 30.f);
    float e = __expf(2.f * x);
    return (e - 1.f) / (e + 1.f);
}

// ---------------- utility kernels ----------------

__global__ void k_zero(int* __restrict__ p, int n) {
    int i = blockIdx.x * 256 + threadIdx.x;
    if (i < n) p[i] = 0;
}

__global__ void k_cast_bf16(const float* __restrict__ in, u16* __restrict__ out, int n4) {
    int i = blockIdx.x * 256 + threadIdx.x;
    if (i < n4) {
        float4 v = ((const float4*)in)[i];
        ushort4 o;
        o.x = f2bf(v.x); o.y = f2bf(v.y); o.z = f2bf(v.z); o.w = f2bf(v.w);
        ((ushort4*)out)[i] = o;
    }
}

__global__ void k_bias_sum(const float* __restrict__ a, const float* __restrict__ b,
                           float* __restrict__ o) {
    int i = blockIdx.x * 256 + threadIdx.x;
    if (i < GH) o[i] = a[i] + b[i];
}

// gather embedding rows (bf16) for the token ids; 2 rows per block
__global__ void k_gather(const u16* __restrict__ embb, const int* __restrict__ ids,
                         u16* __restrict__ xb) {
    int m = blockIdx.x * 2 + (threadIdx.x >> 7);
    int l = threadIdx.x & 127;
    int id = ids[m];
    ((uint2*)(xb + (size_t)m * HH))[l] = ((const uint2*)(embb + (size_t)id * HH))[l];
}

// ---------------- generic NT GEMM: C[M,N] = A[M,K] * B[N,K]^T (+bias)(tanh?) ----------------
// A,B bf16 row-major K-contiguous. 128x128 block tile, 4 waves each 64x64, 16x16x32 MFMA.
__global__ __launch_bounds__(256) void k_gemm_nt(
    const u16* __restrict__ A, const u16* __restrict__ Bm,
    float* __restrict__ Cf, u16* __restrict__ Cb,
    const float* __restrict__ bias, int M, int N, int K, int dotanh)
{
    __shared__ u16 As[128][32];
    __shared__ u16 Bs[128][32];
    const int tid  = threadIdx.x;
    const int lane = tid & 63, wid = tid >> 6;
    const int wm = (wid >> 1) * 64, wn = (wid & 1) * 64;
    const int lr = lane & 15, lq = lane >> 4;
    const int m0 = blockIdx.y * 128, n0 = blockIdx.x * 128;
    const int srow = tid >> 1, skh = (tid & 1) * 16;

    f32x4 acc[4][4];
    for (int i = 0; i < 4; ++i)
        for (int j = 0; j < 4; ++j) { f32x4 z = {0.f, 0.f, 0.f, 0.f}; acc[i][j] = z; }

    const u16* ag = A  + (size_t)(m0 + srow) * K + skh;
    const u16* bg = Bm + (size_t)(n0 + srow) * K + skh;

    for (int k0 = 0; k0 < K; k0 += 32) {
        uint4 av0 = *(const uint4*)(ag + k0);
        uint4 av1 = *(const uint4*)(ag + k0 + 8);
        uint4 bv0 = *(const uint4*)(bg + k0);
        uint4 bv1 = *(const uint4*)(bg + k0 + 8);
        __syncthreads();
        *(uint4*)&As[srow][skh]     = av0;
        *(uint4*)&As[srow][skh + 8] = av1;
        *(uint4*)&Bs[srow][skh]     = bv0;
        *(uint4*)&Bs[srow][skh + 8] = bv1;
        __syncthreads();
        bfrag8 af[4], bf[4];
#pragma unroll
        for (int mt = 0; mt < 4; ++mt) af[mt] = *(const bfrag8*)&As[wm + mt * 16 + lr][lq * 8];
#pragma unroll
        for (int nt = 0; nt < 4; ++nt) bf[nt] = *(const bfrag8*)&Bs[wn + nt * 16 + lr][lq * 8];
#pragma unroll
        for (int mt = 0; mt < 4; ++mt)
#pragma unroll
            for (int nt = 0; nt < 4; ++nt)
                acc[mt][nt] = __builtin_amdgcn_mfma_f32_16x16x32_bf16(af[mt], bf[nt], acc[mt][nt], 0, 0, 0);
    }

#pragma unroll
    for (int mt = 0; mt < 4; ++mt)
#pragma unroll
        for (int nt = 0; nt < 4; ++nt) {
            int col = n0 + wn + nt * 16 + lr;
            float bv = bias ? bias[col] : 0.f;
#pragma unroll
            for (int r = 0; r < 4; ++r) {
                int row = m0 + wm + mt * 16 + lq * 4 + r;
                float v = acc[mt][nt][r] + bv;
                if (dotanh) v = tanhf(v);
                size_t off = (size_t)row * N + col;
                if (Cf) Cf[off] = v;
                if (Cb) Cb[off] = f2bf(v);
            }
        }
}

// ---------------- persistent LSTM ----------------
// 64 blocks; block owns 8 output dims (32 gate rows). W slice lives in registers.
// Handoff of h_{t-1} is FENCE-FREE: h is stored with agent-scope relaxed atomic
// stores (write-through, never dirty in L2), drained with s_waitcnt vmcnt(0) in
// wave 0, then the per-block flag is published with a relaxed agent atomic store.
// Consumers poll flags relaxed and read h with agent-scope relaxed atomic loads
// (bypass stale L1/L2). This removes the per-step buffer_wbl2/buffer_inv that
// the acquire/release agent fences put on the serial dependence chain.
__global__ __launch_bounds__(256) void k_lstm(
    const float* __restrict__ Whh, const float* __restrict__ xg,
    const float* __restrict__ h0, const float* __restrict__ c0,
    float* __restrict__ enc, u16* __restrict__ encb,
    int* __restrict__ flags)
{
    const int tid = threadIdx.x, blk = blockIdx.x;
    const int rq = tid & 7;        // local out-dim d
    const int seg = tid >> 3;      // 0..31, 16-wide k span
    __shared__ float hbuf[4][512];
    __shared__ float red[4][4][8][36];   // [gate][b][d][seg] (+pad)
    __shared__ float gsum[4][4][8];      // [gate][b][d]
    __shared__ float cl[4][8];           // cell state

    // persistent weights: thread holds W_hh[gate*512 + blk*8 + rq][seg*16 .. +15]
    float4 w4[4][4];
#pragma unroll
    for (int g = 0; g < 4; ++g)
#pragma unroll
        for (int q = 0; q < 4; ++q)
            w4[g][q] = *(const float4*)&Whh[(size_t)(g * HH + blk * 8 + rq) * HH + seg * 16 + q * 4];

    if (tid < 32) { int b = tid >> 3, d = tid & 7; cl[b][d] = c0[b * HH + blk * 8 + d]; }

    const int e0 = tid * 8, hb = e0 >> 9, hk = e0 & 511;

    for (int t = 0; t < TT; ++t) {
        // prefetch this step's xg element (per (gate,b,d)) into a register
        float xv = 0.f;
        if (tid < 128) {
            int pd = tid & 7, pg = (tid >> 3) & 3, pb = tid >> 5;
            xv = xg[(size_t)(pb * TT + t) * GH + pg * HH + blk * 8 + pd];
        }
        // obtain h_{t-1}
        if (t == 0) {
            *(float4*)&hbuf[hb][hk]     = *(const float4*)&h0[hb * HH + hk];
            *(float4*)&hbuf[hb][hk + 4] = *(const float4*)&h0[hb * HH + hk + 4];
        } else {
            if (tid < 64) {
                while (__hip_atomic_load(&flags[(t - 1) * LBLK + tid],
                                         __ATOMIC_RELAXED, __HIP_MEMORY_SCOPE_AGENT) == 0) {}
            }
            __syncthreads();   // nobody reads enc[t-1] before wave0 saw all flags
            const float* src = &enc[(size_t)(hb * TT + (t - 1)) * HH + hk];
            float v[8];
#pragma unroll
            for (int j = 0; j < 8; ++j)
                v[j] = __hip_atomic_load(src + j, __ATOMIC_RELAXED, __HIP_MEMORY_SCOPE_AGENT);
#pragma unroll
            for (int j = 0; j < 8; ++j) hbuf[hb][hk + j] = v[j];
        }
        __syncthreads();

        // partial recurrent matvec: acc[gate][b] over this thread's 16-k span
        float acc[4][4] = {};
#pragma unroll
        for (int q = 0; q < 4; ++q) {
            float4 h4[4];
#pragma unroll
            for (int b = 0; b < 4; ++b) h4[b] = *(const float4*)&hbuf[b][seg * 16 + q * 4];
#pragma unroll
            for (int g = 0; g < 4; ++g)
#pragma unroll
                for (int b = 0; b < 4; ++b) {
                    acc[g][b] = fmaf(w4[g][q].x, h4[b].x, acc[g][b]);
                    acc[g][b] = fmaf(w4[g][q].y, h4[b].y, acc[g][b]);
                    acc[g][b] = fmaf(w4[g][q].z, h4[b].z, acc[g][b]);
                    acc[g][b] = fmaf(w4[g][q].w, h4[b].w, acc[g][b]);
                }
        }
#pragma unroll
        for (int g = 0; g < 4; ++g)
#pragma unroll
            for (int b = 0; b < 4; ++b) red[g][b][rq][seg] = acc[g][b];
        __syncthreads();

        // reduce over 32 segs, add xg
        if (tid < 128) {
            int d = tid & 7, g = (tid >> 3) & 3, b = tid >> 5;
            const float4* rp = (const float4*)red[g][b][d];
            float4 s4 = rp[0];
#pragma unroll
            for (int j = 1; j < 8; ++j) {
                float4 v = rp[j];
                s4.x += v.x; s4.y += v.y; s4.z += v.z; s4.w += v.w;
            }
            gsum[g][b][d] = (s4.x + s4.y) + (s4.z + s4.w) + xv;
        }
        __syncthreads();

        // cell update + publish h (wave 0 only; no block barrier needed after —
        // next iteration's poll+syncthreads serializes hbuf/gsum reuse)
        if (tid < 64) {
            if (tid < 32) {
                int b = tid >> 3, d = tid & 7;
                float gi = gsum[0][b][d], gf = gsum[1][b][d], gg = gsum[2][b][d], go = gsum[3][b][d];
                float c  = cl[b][d];
                float cn = sigm(gf) * c + sigm(gi) * tanh_f(gg);
                float hn = sigm(go) * tanh_f(cn);
                cl[b][d] = cn;
                size_t oi = (size_t)(b * TT + t) * HH + blk * 8 + d;
                __hip_atomic_store(&enc[oi], hn, __ATOMIC_RELAXED, __HIP_MEMORY_SCOPE_AGENT);
                encb[oi] = f2bf(hn);
            }
            // drain wave 0's h stores to the coherence point, then publish flag.
            asm volatile("s_waitcnt vmcnt(0)" ::: "memory");
            if (tid == 0)
                __hip_atomic_store(&flags[t * LBLK + blk], 1,
                                   __ATOMIC_RELAXED, __HIP_MEMORY_SCOPE_AGENT);
        }
    }
}

// ---------------- attention scores: s[m] = dot(tanhbuf[m,:], wa2) + ba2 ----------------
__global__ __launch_bounds__(256) void k_scores(const float* __restrict__ tb,
        const float* __restrict__ wa2, const float* __restrict__ ba2, float* __restrict__ sb)
{
    int m = blockIdx.x * 4 + (threadIdx.x >> 6);
    int lane = threadIdx.x & 63;
    const float4* p = (const float4*)(tb + (size_t)m * HH + lane * 8);
    const float4* w = (const float4*)(wa2 + lane * 8);
    float4 v0 = p[0], v1 = p[1], w0 = w[0], w1 = w[1];
    float r = v0.x * w0.x + v0.y * w0.y + v0.z * w0.z + v0.w * w0.w
            + v1.x * w1.x + v1.y * w1.y + v1.z * w1.z + v1.w * w1.w;
    for (int off = 32; off; off >>= 1) r += __shfl_down(r, off);
    if (lane == 0) sb[m] = r + ba2[0];
}

// ---------------- per-batch: e = exp(s - max), invden = 1/cumsum(e) ----------------
__global__ __launch_bounds__(256) void k_softd(const float* __restrict__ s,
        float* __restrict__ e, float* __restrict__ invden)
{
    __shared__ float lred[256];
    __shared__ float pref[256];
    int tid = threadIdx.x;
    for (int b = 0; b < BB; ++b) {
        const float* sb = s + b * TT;
        float m = -1e30f;
#pragma unroll
        for (int j = 0; j < 8; ++j) m = fmaxf(m, sb[tid * 8 + j]);
        lred[tid] = m;
        __syncthreads();
        for (int off = 128; off; off >>= 1) {
            if (tid < off) lred[tid] = fmaxf(lred[tid], lred[tid + off]);
            __syncthreads();
        }
        float mx = lred[0];
        __syncthreads();
        float es[8]; float cs = 0.f;
#pragma unroll
        for (int j = 0; j < 8; ++j) { es[j] = expf(sb[tid * 8 + j] - mx); cs += es[j]; }
        pref[tid] = cs;
        __syncthreads();
        if (tid == 0) {
            float run = 0.f;
            for (int i = 0; i < 256; ++i) { float v = pref[i]; pref[i] = run; run += v; }
        }
        __syncthreads();
        float run = pref[tid];
#pragma unroll
        for (int j = 0; j < 8; ++j) {
            run += es[j];
            e[b * TT + tid * 8 + j] = es[j];
            invden[b * TT + tid * 8 + j] = 1.0f / run;
        }
        __syncthreads();
    }
}

// ---------------- ctx cumsum + build cat = [ctx | enc] (bf16) ----------------
__global__ __launch_bounds__(256) void k_ctx(const u16* __restrict__ encb,
        const float* __restrict__ e, const float* __restrict__ invden, u16* __restrict__ cat)
{
    int g = blockIdx.x * 256 + threadIdx.x;   // 2048 threads = (b,h)
    int b = g >> 9, h = g & 511;
    float acc = 0.f;
    for (int t = 0; t < TT; ++t) {
        size_t m = (size_t)b * TT + t;
        u16 hu = encb[m * HH + h];
        acc = fmaf(e[m], bf2f(hu), acc);
        float ctx = acc * invden[m];
        cat[m * 1024 + h]       = f2bf(ctx);
        cat[m * 1024 + 512 + h] = hu;
    }
}

// ---------------- host launcher ----------------
extern "C" void kernel_launch(void* const* d_in, const int* in_sizes, int n_in,
                              void* d_out, int out_size, void* d_ws, size_t ws_size,
                              hipStream_t stream)
{
    const int*   ids   = (const int*)  d_in[0];
    const float* h0    = (const float*)d_in[1];
    const float* c0    = (const float*)d_in[2];
    const float* emb   = (const float*)d_in[3];
    const float* W_ih  = (const float*)d_in[4];
    const float* W_hh  = (const float*)d_in[5];
    const float* b_ih  = (const float*)d_in[6];
    const float* b_hh  = (const float*)d_in[7];
    const float* Wa1   = (const float*)d_in[8];
    const float* ba1   = (const float*)d_in[9];
    const float* wa2   = (const float*)d_in[10];
    const float* ba2   = (const float*)d_in[11];
    const float* Wc    = (const float*)d_in[12];
    const float* bc    = (const float*)d_in[13];
    const float* b_dec = (const float*)d_in[14];
    float* out = (float*)d_out;

    // workspace carve (~180 MB total)
    char* w = (char*)d_ws;
    auto carve = [&](size_t bytes) { char* p = w; w += (bytes + 255) & ~(size_t)255; return p; };
    int*  flags  = (int*) carve((size_t)LBLK * TT * 4);
    u16*  embb   = (u16*) carve((size_t)VV * HH * 2);
    u16*  wihb   = (u16*) carve((size_t)GH * HH * 2);
    u16*  wa1b   = (u16*) carve((size_t)HH * HH * 2);
    u16*  wcb    = (u16*) carve((size_t)HH * 1024 * 2);
    float* bsum  = (float*)carve((size_t)GH * 4);
    u16*  xb     = (u16*) carve((size_t)MM * HH * 2);
    float* xg    = (float*)carve((size_t)MM * GH * 4);
    float* enc   = (float*)carve((size_t)MM * HH * 4);
    u16*  encb   = (u16*) carve((size_t)MM * HH * 2);
    float* tanhb = (float*)carve((size_t)MM * HH * 4);
    float* sbuf  = (float*)carve((size_t)MM * 4);
    float* ebuf  = (float*)carve((size_t)MM * 4);
    float* invd  = (float*)carve((size_t)MM * 4);
    u16*  catb   = (u16*) carve((size_t)MM * 1024 * 2);
    u16*  combb  = (u16*) carve((size_t)MM * HH * 2);

    k_zero<<<dim3(512), dim3(256), 0, stream>>>(flags, LBLK * TT);
    k_cast_bf16<<<dim3(VV * HH / 4 / 256), dim3(256), 0, stream>>>(emb, embb, VV * HH / 4);
    k_cast_bf16<<<dim3(GH * HH / 4 / 256), dim3(256), 0, stream>>>(W_ih, wihb, GH * HH / 4);
    k_cast_bf16<<<dim3(HH * HH / 4 / 256), dim3(256), 0, stream>>>(Wa1, wa1b, HH * HH / 4);
    k_cast_bf16<<<dim3(HH * 1024 / 4 / 256), dim3(256), 0, stream>>>(Wc, wcb, HH * 1024 / 4);
    k_bias_sum<<<dim3(8), dim3(256), 0, stream>>>(b_ih, b_hh, bsum);
    k_gather<<<dim3(MM / 2), dim3(256), 0, stream>>>(embb, ids, xb);

    // xg = x @ W_ih^T + (b_ih + b_hh)
    k_gemm_nt<<<dim3(GH / 128, MM / 128), dim3(256), 0, stream>>>(
        xb, wihb, xg, nullptr, bsum, MM, GH, HH, 0);

    // LSTM scan
    k_lstm<<<dim3(LBLK), dim3(256), 0, stream>>>(W_hh, xg, h0, c0, enc, encb, flags);

    // tanh(enc @ Wa1^T + ba1)
    k_gemm_nt<<<dim3(HH / 128, MM / 128), dim3(256), 0, stream>>>(
        encb, wa1b, tanhb, nullptr, ba1, MM, HH, HH, 1);

    k_scores<<<dim3(MM / 4), dim3(256), 0, stream>>>(tanhb, wa2, ba2, sbuf);
    k_softd<<<dim3(1), dim3(256), 0, stream>>>(sbuf, ebuf, invd);
    k_ctx<<<dim3(8), dim3(256), 0, stream>>>(encb, ebuf, invd, catb);

    // combined = tanh(cat @ Wc^T + bc)  (bf16 out)
    k_gemm_nt<<<dim3(HH / 128, MM / 128), dim3(256), 0, stream>>>(
        catb, wcb, nullptr, combb, bc, MM, HH, 1024, 1);

    // decoded = combined @ emb^T + b_dec
    k_gemm_nt<<<dim3(VV / 128, MM / 128), dim3(256), 0, stream>>>(
        combb, embb, out, nullptr, b_dec, MM, VV, HH, 0);
}

// Round 2
// 10393.877 us; speedup vs baseline: 1.4815x; 1.0798x over previous
//
#include <hip/hip_runtime.h>

// Problem constants
#define BB 4
#define TT 2048
#define HH 512
#define GH 2048       // 4*H
#define VV 32000
#define MM 8192       // B*T
#define LBLK 64       // LSTM persistent blocks
#define CANARY 0x7F800001u   // sNaN bit pattern: impossible for h = sigm*tanh in (-1,1)

typedef unsigned short u16;
typedef short bfrag8 __attribute__((ext_vector_type(8)));   // 8 x bf16 MFMA operand
typedef float f32x4  __attribute__((ext_vector_type(4)));   // MFMA accumulator

static __device__ __forceinline__ u16 f2bf(float f) {
    unsigned x = __float_as_uint(f);
    unsigned r = x + 0x7fffu + ((x >> 16) & 1u);   // round-to-nearest-even
    return (u16)(r >> 16);
}
static __device__ __forceinline__ float bf2f(u16 u) {
    return __uint_as_float(((unsigned)u) << 16);
}
static __device__ __forceinline__ float sigm(float x) {
    return 1.0f / (1.0f + __expf(-x));
}
static __device__ __forceinline__ float tanh_f(float x) {
    x = fminf(fmaxf(x, -30.f), 30.f);
    float e = __expf(2.f * x);
    return (e - 1.f) / (e + 1.f);
}

// ---------------- utility kernels ----------------

__global__ void k_fill(unsigned* __restrict__ p, unsigned v, int n4) {
    int i = blockIdx.x * 256 + threadIdx.x;
    if (i < n4) {
        uint4 q = {v, v, v, v};
        ((uint4*)p)[i] = q;
    }
}

__global__ void k_cast_bf16(const float* __restrict__ in, u16* __restrict__ out, int n4) {
    int i = blockIdx.x * 256 + threadIdx.x;
    if (i < n4) {
        float4 v = ((const float4*)in)[i];
        ushort4 o;
        o.x = f2bf(v.x); o.y = f2bf(v.y); o.z = f2bf(v.z); o.w = f2bf(v.w);
        ((ushort4*)out)[i] = o;
    }
}

__global__ void k_bias_sum(const float* __restrict__ a, const float* __restrict__ b,
                           float* __restrict__ o) {
    int i = blockIdx.x * 256 + threadIdx.x;
    if (i < GH) o[i] = a[i] + b[i];
}

// gather embedding rows (bf16) for the token ids; 2 rows per block
__global__ void k_gather(const u16* __restrict__ embb, const int* __restrict__ ids,
                         u16* __restrict__ xb) {
    int m = blockIdx.x * 2 + (threadIdx.x >> 7);
    int l = threadIdx.x & 127;
    int id = ids[m];
    ((uint2*)(xb + (size_t)m * HH))[l] = ((const uint2*)(embb + (size_t)id * HH))[l];
}

// ---------------- generic NT GEMM: C[M,N] = A[M,K] * B[N,K]^T (+bias)(tanh?) ----------------
// A,B bf16 row-major K-contiguous. 128x128 block tile, 4 waves each 64x64, 16x16x32 MFMA.
__global__ __launch_bounds__(256) void k_gemm_nt(
    const u16* __restrict__ A, const u16* __restrict__ Bm,
    float* __restrict__ Cf, u16* __restrict__ Cb,
    const float* __restrict__ bias, int M, int N, int K, int dotanh)
{
    __shared__ u16 As[128][32];
    __shared__ u16 Bs[128][32];
    const int tid  = threadIdx.x;
    const int lane = tid & 63, wid = tid >> 6;
    const int wm = (wid >> 1) * 64, wn = (wid & 1) * 64;
    const int lr = lane & 15, lq = lane >> 4;
    const int m0 = blockIdx.y * 128, n0 = blockIdx.x * 128;
    const int srow = tid >> 1, skh = (tid & 1) * 16;

    f32x4 acc[4][4];
    for (int i = 0; i < 4; ++i)
        for (int j = 0; j < 4; ++j) { f32x4 z = {0.f, 0.f, 0.f, 0.f}; acc[i][j] = z; }

    const u16* ag = A  + (size_t)(m0 + srow) * K + skh;
    const u16* bg = Bm + (size_t)(n0 + srow) * K + skh;

    for (int k0 = 0; k0 < K; k0 += 32) {
        uint4 av0 = *(const uint4*)(ag + k0);
        uint4 av1 = *(const uint4*)(ag + k0 + 8);
        uint4 bv0 = *(const uint4*)(bg + k0);
        uint4 bv1 = *(const uint4*)(bg + k0 + 8);
        __syncthreads();
        *(uint4*)&As[srow][skh]     = av0;
        *(uint4*)&As[srow][skh + 8] = av1;
        *(uint4*)&Bs[srow][skh]     = bv0;
        *(uint4*)&Bs[srow][skh + 8] = bv1;
        __syncthreads();
        bfrag8 af[4], bf[4];
#pragma unroll
        for (int mt = 0; mt < 4; ++mt) af[mt] = *(const bfrag8*)&As[wm + mt * 16 + lr][lq * 8];
#pragma unroll
        for (int nt = 0; nt < 4; ++nt) bf[nt] = *(const bfrag8*)&Bs[wn + nt * 16 + lr][lq * 8];
#pragma unroll
        for (int mt = 0; mt < 4; ++mt)
#pragma unroll
            for (int nt = 0; nt < 4; ++nt)
                acc[mt][nt] = __builtin_amdgcn_mfma_f32_16x16x32_bf16(af[mt], bf[nt], acc[mt][nt], 0, 0, 0);
    }

#pragma unroll
    for (int mt = 0; mt < 4; ++mt)
#pragma unroll
        for (int nt = 0; nt < 4; ++nt) {
            int col = n0 + wn + nt * 16 + lr;
            float bv = bias ? bias[col] : 0.f;
#pragma unroll
            for (int r = 0; r < 4; ++r) {
                int row = m0 + wm + mt * 16 + lq * 4 + r;
                float v = acc[mt][nt][r] + bv;
                if (dotanh) v = tanhf(v);
                size_t off = (size_t)row * N + col;
                if (Cf) Cf[off] = v;
                if (Cb) Cb[off] = f2bf(v);
            }
        }
}

// ---------------- persistent LSTM ----------------
// 64 blocks; block owns 8 output dims (32 gate rows). W slice lives in registers.
// Handoff of h_{t-1}: POLL-THE-DATA. enc is pre-filled with a NaN canary that
// h = sigm(o)*tanh(c) (strictly in (-1,1), never NaN) can never equal.
// Producers fire relaxed agent-scope stores of h and move on — no drain, no
// flag, no fence. Consumers poll exactly the 8 dwords they consume until all
// are non-canary. Each word transitions canary->final exactly once, so
// per-location coherence suffices: no cross-location ordering needed.
// This collapses the 3-hop store->flag->data chain to one visibility latency.
__global__ __launch_bounds__(256) void k_lstm(
    const float* __restrict__ Whh, const float* __restrict__ xg,
    const float* __restrict__ h0, const float* __restrict__ c0,
    float* __restrict__ enc, u16* __restrict__ encb)
{
    const int tid = threadIdx.x, blk = blockIdx.x;
    const int rq = tid & 7;        // local out-dim d
    const int seg = tid >> 3;      // 0..31, 16-wide k span
    __shared__ float hbuf[4][512];
    __shared__ float red[4][4][8][36];   // [gate][b][d][seg] (+pad)
    __shared__ float gsum[4][4][8];      // [gate][b][d]
    __shared__ float cl[4][8];           // cell state

    // persistent weights: thread holds W_hh[gate*512 + blk*8 + rq][seg*16 .. +15]
    float4 w4[4][4];
#pragma unroll
    for (int g = 0; g < 4; ++g)
#pragma unroll
        for (int q = 0; q < 4; ++q)
            w4[g][q] = *(const float4*)&Whh[(size_t)(g * HH + blk * 8 + rq) * HH + seg * 16 + q * 4];

    if (tid < 32) { int b = tid >> 3, d = tid & 7; cl[b][d] = c0[b * HH + blk * 8 + d]; }

    const int e0 = tid * 8, hb = e0 >> 9, hk = e0 & 511;

    for (int t = 0; t < TT; ++t) {
        // prefetch this step's xg element (per (gate,b,d)) into a register
        float xv = 0.f;
        if (tid < 128) {
            int pd = tid & 7, pg = (tid >> 3) & 3, pb = tid >> 5;
            xv = xg[(size_t)(pb * TT + t) * GH + pg * HH + blk * 8 + pd];
        }
        // obtain h_{t-1}
        if (t == 0) {
            *(float4*)&hbuf[hb][hk]     = *(const float4*)&h0[hb * HH + hk];
            *(float4*)&hbuf[hb][hk + 4] = *(const float4*)&h0[hb * HH + hk + 4];
        } else {
            // poll-the-data: every thread polls its own 8 dwords of enc[t-1]
            const int* srci = (const int*)&enc[(size_t)(hb * TT + (t - 1)) * HH + hk];
            int v[8];
            bool ok;
            do {
                ok = true;
#pragma unroll
                for (int j = 0; j < 8; ++j) {
                    v[j] = __hip_atomic_load(srci + j, __ATOMIC_RELAXED,
                                             __HIP_MEMORY_SCOPE_AGENT);
                    ok = ok && ((unsigned)v[j] != CANARY);
                }
            } while (!ok);
#pragma unroll
            for (int j = 0; j < 8; ++j) hbuf[hb][hk + j] = __int_as_float(v[j]);
        }
        __syncthreads();

        // partial recurrent matvec: acc[gate][b] over this thread's 16-k span
        float acc[4][4] = {};
#pragma unroll
        for (int q = 0; q < 4; ++q) {
            float4 h4[4];
#pragma unroll
            for (int b = 0; b < 4; ++b) h4[b] = *(const float4*)&hbuf[b][seg * 16 + q * 4];
#pragma unroll
            for (int g = 0; g < 4; ++g)
#pragma unroll
                for (int b = 0; b < 4; ++b) {
                    acc[g][b] = fmaf(w4[g][q].x, h4[b].x, acc[g][b]);
                    acc[g][b] = fmaf(w4[g][q].y, h4[b].y, acc[g][b]);
                    acc[g][b] = fmaf(w4[g][q].z, h4[b].z, acc[g][b]);
                    acc[g][b] = fmaf(w4[g][q].w, h4[b].w, acc[g][b]);
                }
        }
#pragma unroll
        for (int g = 0; g < 4; ++g)
#pragma unroll
            for (int b = 0; b < 4; ++b) red[g][b][rq][seg] = acc[g][b];
        __syncthreads();

        // reduce over 32 segs, add xg
        if (tid < 128) {
            int d = tid & 7, g = (tid >> 3) & 3, b = tid >> 5;
            const float4* rp = (const float4*)red[g][b][d];
            float4 s4 = rp[0];
#pragma unroll
            for (int j = 1; j < 8; ++j) {
                float4 v = rp[j];
                s4.x += v.x; s4.y += v.y; s4.z += v.z; s4.w += v.w;
            }
            gsum[g][b][d] = (s4.x + s4.y) + (s4.z + s4.w) + xv;
        }
        __syncthreads();

        // cell update + publish h: fire-and-forget agent-scope stores.
        // No drain, no flag. Next iteration's barriers serialize LDS reuse.
        if (tid < 32) {
            int b = tid >> 3, d = tid & 7;
            float gi = gsum[0][b][d], gf = gsum[1][b][d], gg = gsum[2][b][d], go = gsum[3][b][d];
            float c  = cl[b][d];
            float cn = sigm(gf) * c + sigm(gi) * tanh_f(gg);
            float hn = sigm(go) * tanh_f(cn);
            cl[b][d] = cn;
            size_t oi = (size_t)(b * TT + t) * HH + blk * 8 + d;
            __hip_atomic_store(&enc[oi], hn, __ATOMIC_RELAXED, __HIP_MEMORY_SCOPE_AGENT);
            encb[oi] = f2bf(hn);
        }
    }
}

// ---------------- attention scores: s[m] = dot(tanhbuf[m,:], wa2) + ba2 ----------------
__global__ __launch_bounds__(256) void k_scores(const float* __restrict__ tb,
        const float* __restrict__ wa2, const float* __restrict__ ba2, float* __restrict__ sb)
{
    int m = blockIdx.x * 4 + (threadIdx.x >> 6);
    int lane = threadIdx.x & 63;
    const float4* p = (const float4*)(tb + (size_t)m * HH + lane * 8);
    const float4* w = (const float4*)(wa2 + lane * 8);
    float4 v0 = p[0], v1 = p[1], w0 = w[0], w1 = w[1];
    float r = v0.x * w0.x + v0.y * w0.y + v0.z * w0.z + v0.w * w0.w
            + v1.x * w1.x + v1.y * w1.y + v1.z * w1.z + v1.w * w1.w;
    for (int off = 32; off; off >>= 1) r += __shfl_down(r, off);
    if (lane == 0) sb[m] = r + ba2[0];
}

// ---------------- per-batch: e = exp(s - max), invden = 1/cumsum(e) ----------------
__global__ __launch_bounds__(256) void k_softd(const float* __restrict__ s,
        float* __restrict__ e, float* __restrict__ invden)
{
    __shared__ float lred[256];
    __shared__ float pref[256];
    int tid = threadIdx.x;
    for (int b = 0; b < BB; ++b) {
        const float* sb = s + b * TT;
        float m = -1e30f;
#pragma unroll
        for (int j = 0; j < 8; ++j) m = fmaxf(m, sb[tid * 8 + j]);
        lred[tid] = m;
        __syncthreads();
        for (int off = 128; off; off >>= 1) {
            if (tid < off) lred[tid] = fmaxf(lred[tid], lred[tid + off]);
            __syncthreads();
        }
        float mx = lred[0];
        __syncthreads();
        float es[8]; float cs = 0.f;
#pragma unroll
        for (int j = 0; j < 8; ++j) { es[j] = expf(sb[tid * 8 + j] - mx); cs += es[j]; }
        pref[tid] = cs;
        __syncthreads();
        if (tid == 0) {
            float run = 0.f;
            for (int i = 0; i < 256; ++i) { float v = pref[i]; pref[i] = run; run += v; }
        }
        __syncthreads();
        float run = pref[tid];
#pragma unroll
        for (int j = 0; j < 8; ++j) {
            run += es[j];
            e[b * TT + tid * 8 + j] = es[j];
            invden[b * TT + tid * 8 + j] = 1.0f / run;
        }
        __syncthreads();
    }
}

// ---------------- ctx cumsum + build cat = [ctx | enc] (bf16) ----------------
__global__ __launch_bounds__(256) void k_ctx(const u16* __restrict__ encb,
        const float* __restrict__ e, const float* __restrict__ invden, u16* __restrict__ cat)
{
    int g = blockIdx.x * 256 + threadIdx.x;   // 2048 threads = (b,h)
    int b = g >> 9, h = g & 511;
    float acc = 0.f;
    for (int t = 0; t < TT; ++t) {
        size_t m = (size_t)b * TT + t;
        u16 hu = encb[m * HH + h];
        acc = fmaf(e[m], bf2f(hu), acc);
        float ctx = acc * invden[m];
        cat[m * 1024 + h]       = f2bf(ctx);
        cat[m * 1024 + 512 + h] = hu;
    }
}

// ---------------- host launcher ----------------
extern "C" void kernel_launch(void* const* d_in, const int* in_sizes, int n_in,
                              void* d_out, int out_size, void* d_ws, size_t ws_size,
                              hipStream_t stream)
{
    const int*   ids   = (const int*)  d_in[0];
    const float* h0    = (const float*)d_in[1];
    const float* c0    = (const float*)d_in[2];
    const float* emb   = (const float*)d_in[3];
    const float* W_ih  = (const float*)d_in[4];
    const float* W_hh  = (const float*)d_in[5];
    const float* b_ih  = (const float*)d_in[6];
    const float* b_hh  = (const float*)d_in[7];
    const float* Wa1   = (const float*)d_in[8];
    const float* ba1   = (const float*)d_in[9];
    const float* wa2   = (const float*)d_in[10];
    const float* ba2   = (const float*)d_in[11];
    const float* Wc    = (const float*)d_in[12];
    const float* bc    = (const float*)d_in[13];
    const float* b_dec = (const float*)d_in[14];
    float* out = (float*)d_out;

    // workspace carve (~180 MB total)
    char* w = (char*)d_ws;
    auto carve = [&](size_t bytes) { char* p = w; w += (bytes + 255) & ~(size_t)255; return p; };
    u16*  embb   = (u16*) carve((size_t)VV * HH * 2);
    u16*  wihb   = (u16*) carve((size_t)GH * HH * 2);
    u16*  wa1b   = (u16*) carve((size_t)HH * HH * 2);
    u16*  wcb    = (u16*) carve((size_t)HH * 1024 * 2);
    float* bsum  = (float*)carve((size_t)GH * 4);
    u16*  xb     = (u16*) carve((size_t)MM * HH * 2);
    float* xg    = (float*)carve((size_t)MM * GH * 4);
    float* enc   = (float*)carve((size_t)MM * HH * 4);
    u16*  encb   = (u16*) carve((size_t)MM * HH * 2);
    float* tanhb = (float*)carve((size_t)MM * HH * 4);
    float* sbuf  = (float*)carve((size_t)MM * 4);
    float* ebuf  = (float*)carve((size_t)MM * 4);
    float* invd  = (float*)carve((size_t)MM * 4);
    u16*  catb   = (u16*) carve((size_t)MM * 1024 * 2);
    u16*  combb  = (u16*) carve((size_t)MM * HH * 2);

    // pre-fill enc with the NaN canary (MM*HH dwords, uint4-vectorized)
    k_fill<<<dim3(MM * HH / 4 / 256), dim3(256), 0, stream>>>(
        (unsigned*)enc, CANARY, MM * HH / 4);
    k_cast_bf16<<<dim3(VV * HH / 4 / 256), dim3(256), 0, stream>>>(emb, embb, VV * HH / 4);
    k_cast_bf16<<<dim3(GH * HH / 4 / 256), dim3(256), 0, stream>>>(W_ih, wihb, GH * HH / 4);
    k_cast_bf16<<<dim3(HH * HH / 4 / 256), dim3(256), 0, stream>>>(Wa1, wa1b, HH * HH / 4);
    k_cast_bf16<<<dim3(HH * 1024 / 4 / 256), dim3(256), 0, stream>>>(Wc, wcb, HH * 1024 / 4);
    k_bias_sum<<<dim3(8), dim3(256), 0, stream>>>(b_ih, b_hh, bsum);
    k_gather<<<dim3(MM / 2), dim3(256), 0, stream>>>(embb, ids, xb);

    // xg = x @ W_ih^T + (b_ih + b_hh)
    k_gemm_nt<<<dim3(GH / 128, MM / 128), dim3(256), 0, stream>>>(
        xb, wihb, xg, nullptr, bsum, MM, GH, HH, 0);

    // LSTM scan
    k_lstm<<<dim3(LBLK), dim3(256), 0, stream>>>(W_hh, xg, h0, c0, enc, encb);

    // tanh(enc @ Wa1^T + ba1)
    k_gemm_nt<<<dim3(HH / 128, MM / 128), dim3(256), 0, stream>>>(
        encb, wa1b, tanhb, nullptr, ba1, MM, HH, HH, 1);

    k_scores<<<dim3(MM / 4), dim3(256), 0, stream>>>(tanhb, wa2, ba2, sbuf);
    k_softd<<<dim3(1), dim3(256), 0, stream>>>(sbuf, ebuf, invd);
    k_ctx<<<dim3(8), dim3(256), 0, stream>>>(encb, ebuf, invd, catb);

    // combined = tanh(cat @ Wc^T + bc)  (bf16 out)
    k_gemm_nt<<<dim3(HH / 128, MM / 128), dim3(256), 0, stream>>>(
        catb, wcb, nullptr, combb, bc, MM, HH, 1024, 1);

    // decoded = combined @ emb^T + b_dec
    k_gemm_nt<<<dim3(VV / 128, MM / 128), dim3(256), 0, stream>>>(
        combb, embb, out, nullptr, b_dec, MM, VV, HH, 0);
}